// Round 1
// baseline (529.346 us; speedup 1.0000x reference)
//
#include <hip/hip_runtime.h>

typedef unsigned short ushort_t;
typedef unsigned int uint_t;
typedef __attribute__((ext_vector_type(8))) short bf16x8;
typedef __attribute__((ext_vector_type(4))) float f32x4;
typedef __attribute__((ext_vector_type(2))) float f32x2;

#define N_NODES 50000
#define N_EDGES 800000
#define BN_EPS 1e-5f

// ws layout (floats): [0 .. 4800000) h buffer (node_aggr writes h = x + sum(msg),
//                     mlp overwrites with o rows)   [4800000..4800192) BN stats
//                     [4800192] edge_index dtype flag (1 = int64)
#define OFF_STATS 4800000
#define OFF_FLAG  4800192

// scratch carved out of d_out (ints) — consumed before bn_kernel writes out:
//   sorted_eid [0, 800000)   offsets [800000, 850001)
//   deg [850016, 900016)     cursor [900032, 950032)
#define SC_SORTED  0
#define SC_OFFSETS 800000
#define SC_DEG     850016
#define SC_CURSOR  900032

__device__ __forceinline__ ushort_t f2bf(float f) {
    uint_t u = __float_as_uint(f);
    uint_t r = ((u >> 16) & 1u) + 0x7fffu;  // RNE
    return (ushort_t)((u + r) >> 16);
}

// ---------------------------------------------------------------------------
// detect: int64 vs int32 edge_index. int64 data (<50000) => every odd int32
// word is 0. 4096 samples, all < 1.6M (in-bounds under either layout).
// ---------------------------------------------------------------------------
__global__ __launch_bounds__(1024) void detect_kernel(const int* __restrict__ ei,
                                                      int* __restrict__ flag) {
    __shared__ int any_nonzero;
    if (threadIdx.x == 0) any_nonzero = 0;
    __syncthreads();
    int nz = 0;
#pragma unroll
    for (int q = 0; q < 4; ++q) {
        int p = 1 + 2 * (threadIdx.x * 4 + q) * 195;  // odd, <= 1,598,051
        if (ei[p] != 0) nz = 1;
    }
    if (nz) atomicOr(&any_nonzero, 1);
    __syncthreads();
    if (threadIdx.x == 0) *flag = any_nonzero ? 0 : 1;
}

// ---------------------------------------------------------------------------
// hist: deg[dst]++ for every valid edge (same validity predicate as scatter
// and as the old edge kernel: both endpoints in range).
// ---------------------------------------------------------------------------
__global__ __launch_bounds__(256) void hist_kernel(const int* __restrict__ ei,
                                                   const int* __restrict__ flag,
                                                   int* __restrict__ deg) {
    const int is64 = *flag;
    const int stride = gridDim.x * blockDim.x;
    for (int e = blockIdx.x * blockDim.x + threadIdx.x; e < N_EDGES; e += stride) {
        int s, d;
        if (is64) { s = ei[2 * e]; d = ei[2 * N_EDGES + 2 * e]; }
        else      { s = ei[e];     d = ei[N_EDGES + e]; }
        if ((uint_t)s < N_NODES && (uint_t)d < N_NODES) atomicAdd(&deg[d], 1);
    }
}

// ---------------------------------------------------------------------------
// scan: exclusive prefix sum of deg[50000] -> offsets[50001], copy -> cursor.
// Single block, 1024 threads, 49 elems/thread + Hillis-Steele block scan.
// ---------------------------------------------------------------------------
__global__ __launch_bounds__(1024) void scan_kernel(const int* __restrict__ deg,
                                                    int* __restrict__ offsets,
                                                    int* __restrict__ cursor) {
    __shared__ int lds[1024];
    const int tid = threadIdx.x;
    const int lo = tid * 49;
    int hi = lo + 49; if (hi > N_NODES) hi = N_NODES;
    int s = 0;
    for (int i = lo; i < hi; ++i) s += deg[i];
    int run = s;
    for (int off = 1; off < 1024; off <<= 1) {
        lds[tid] = run;
        __syncthreads();
        if (tid >= off) run += lds[tid - off];
        __syncthreads();
    }
    int base = run - s;  // exclusive prefix for this thread's chunk
    for (int i = lo; i < hi; ++i) {
        offsets[i] = base;
        cursor[i] = base;
        base += deg[i];
    }
    if (tid == 1023) offsets[N_NODES] = run;
}

// ---------------------------------------------------------------------------
// scatter: pos = cursor[dst]++; sorted_eid[pos] = e.  Order within a node is
// arbitrary (fp sum is order-independent up to rounding, same as atomics).
// ---------------------------------------------------------------------------
__global__ __launch_bounds__(256) void scatter_kernel(const int* __restrict__ ei,
                                                      const int* __restrict__ flag,
                                                      int* __restrict__ cursor,
                                                      int* __restrict__ sorted_eid) {
    const int is64 = *flag;
    const int stride = gridDim.x * blockDim.x;
    for (int e = blockIdx.x * blockDim.x + threadIdx.x; e < N_EDGES; e += stride) {
        int s, d;
        if (is64) { s = ei[2 * e]; d = ei[2 * N_EDGES + 2 * e]; }
        else      { s = ei[e];     d = ei[N_EDGES + e]; }
        if ((uint_t)s < N_NODES && (uint_t)d < N_NODES) {
            int pos = atomicAdd(&cursor[d], 1);
            sorted_eid[pos] = e;
        }
    }
}

// ---------------------------------------------------------------------------
// node_aggr: one wave per node (grid-stride). For each 16-edge chunk of the
// node's sorted edge list:
//   proj[16e x 96f] = ea[eids] @ We  via 6x mfma 16x16x32 bf16 (same frag
//   mapping as the proven edge kernel: A[m=t][k=q*8+j], C row m=q*4+r col t).
//   part[f] += relu(proj + be + x[src])  summed over this quad's 4 rows.
// Butterfly across quads (lane^16, lane^32), add x[n], ONE plain store per
// element: hbuf[n] = x[n] + sum(msg).  No float atomics at all.
// ---------------------------------------------------------------------------
__global__ __launch_bounds__(256) void node_aggr_kernel(
    const float* __restrict__ x, const int* __restrict__ ei,
    const float* __restrict__ ea, const float* __restrict__ We,
    const float* __restrict__ be, const int* __restrict__ sorted_eid,
    const int* __restrict__ offsets, const int* __restrict__ flag,
    float* __restrict__ hbuf) {
    const int lane = threadIdx.x & 63;
    const int q = lane >> 4;   // quad 0..3
    const int t = lane & 15;   // 0..15
    const int wav = blockIdx.x * (blockDim.x >> 6) + (threadIdx.x >> 6);
    const int nwav = gridDim.x * (blockDim.x >> 6);
    const int is64 = *flag;

    bf16x8 Bf[6];
    float ben[6];
#pragma unroll
    for (int f = 0; f < 6; ++f) {
        const int n = t + 16 * f;
#pragma unroll
        for (int j = 0; j < 8; ++j) {
            const int k = q * 8 + j;
            Bf[f][j] = (short)f2bf(We[k * 96 + n]);
        }
        ben[f] = be[n];
    }

    for (int n = wav; n < N_NODES; n += nwav) {
        const int off = offsets[n];
        const int deg = offsets[n + 1] - off;

        float part[6];
#pragma unroll
        for (int f = 0; f < 6; ++f) part[f] = 0.f;

        for (int c0 = 0; c0 < deg; c0 += 16) {
            const int rem = deg - c0;  // >= 1; valid slots = min(rem,16)
            int eid_t = -1, src_t = -1;
            if (t < rem) {
                eid_t = sorted_eid[off + c0 + t];
                src_t = is64 ? ei[2 * eid_t] : ei[eid_t];
            }
            bf16x8 A = {0, 0, 0, 0, 0, 0, 0, 0};
            if (eid_t >= 0) {
                const float* row = ea + (size_t)eid_t * 32 + q * 8;
                f32x4 a0 = *(const f32x4*)(row);
                f32x4 a1 = *(const f32x4*)(row + 4);
#pragma unroll
                for (int j = 0; j < 4; ++j) {
                    A[j] = (short)f2bf(a0[j]);
                    A[4 + j] = (short)f2bf(a1[j]);
                }
            }

            f32x4 acc[6];
#pragma unroll
            for (int f = 0; f < 6; ++f) {
                f32x4 z = {0.f, 0.f, 0.f, 0.f};
                acc[f] = __builtin_amdgcn_mfma_f32_16x16x32_bf16(A, Bf[f], z, 0, 0, 0);
            }

            // srcs of this quad's 4 rows, fetched cross-lane while all lanes
            // are active (slot m is held by lane m, m<16).
            int s_r[4];
#pragma unroll
            for (int r = 0; r < 4; ++r) s_r[r] = __shfl(src_t, q * 4 + r);

#pragma unroll
            for (int r = 0; r < 4; ++r) {
                const int m = q * 4 + r;
                if (m < rem) {
                    const float* xrow = x + (size_t)s_r[r] * 96;
#pragma unroll
                    for (int f = 0; f < 6; ++f) {
                        float v = acc[f][r] + ben[f] + xrow[t + 16 * f];
                        part[f] += v > 0.f ? v : 0.f;
                    }
                }
            }
        }

        // reduce across the 4 quads (rows 0..15 of the chunk tiles)
#pragma unroll
        for (int f = 0; f < 6; ++f) {
            part[f] += __shfl_xor(part[f], 16);
            part[f] += __shfl_xor(part[f], 32);
        }

        if (q == 0) {
            const float* xn = x + (size_t)n * 96;
            float* hn = hbuf + (size_t)n * 96;
#pragma unroll
            for (int f = 0; f < 6; ++f) {
                const int col = t + 16 * f;
                hn[col] = part[f] + xn[col];
            }
        }
    }
}

// ---------------------------------------------------------------------------
// mlp v2 (fp32, register-tiled): 64-node tile, 256 threads.
// thread (fg=tid&15, ng=tid>>4): 4 nodes x 6 features, 24 accumulators.
// hsT[k][n] (pad 68: bank = (4k+n)%32, conflict-free reads), Ws[96*96].
// Per k-step: 1x b128 (hsT) + 3x b64 (Ws) for 24 MACs.
// Writes o rows back into buf (disjoint rows per block; staged first).
// ---------------------------------------------------------------------------
#define MTILE 64
__global__ __launch_bounds__(256) void mlp_kernel(
    float* buf, const float* __restrict__ W1g, const float* __restrict__ b1g,
    const float* __restrict__ W2g, const float* __restrict__ b2g,
    float* __restrict__ stats) {
    __shared__ float Ws[96 * 96];
    __shared__ float hsT[96][68];

    const int tid = threadIdx.x;
    const int fg = tid & 15;
    const int ng = tid >> 4;
    const int n0 = blockIdx.x * MTILE;

    for (int i = tid; i < 96 * 96 / 4; i += 256)
        ((f32x4*)Ws)[i] = ((const f32x4*)W1g)[i];
    for (int i = tid; i < MTILE * 96 / 4; i += 256) {
        const int base = i * 4;
        const int nn = base / 96, k = base - nn * 96;
        f32x4 v = {0.f, 0.f, 0.f, 0.f};
        if (n0 + nn < N_NODES)
            v = *(const f32x4*)(buf + (size_t)(n0 + nn) * 96 + k);
        hsT[k][nn] = v[0]; hsT[k + 1][nn] = v[1];
        hsT[k + 2][nn] = v[2]; hsT[k + 3][nn] = v[3];
    }
    __syncthreads();

    float acc[4][6];
#pragma unroll
    for (int ff = 0; ff < 6; ++ff) {
        const float b = b1g[6 * fg + ff];
        acc[0][ff] = b; acc[1][ff] = b; acc[2][ff] = b; acc[3][ff] = b;
    }
    for (int k = 0; k < 96; ++k) {
        const f32x4 a = *(const f32x4*)&hsT[k][4 * ng];
        const float* wr = &Ws[k * 96 + 6 * fg];
        const f32x2 w01 = *(const f32x2*)(wr);
        const f32x2 w23 = *(const f32x2*)(wr + 2);
        const f32x2 w45 = *(const f32x2*)(wr + 4);
        const float w[6] = {w01[0], w01[1], w23[0], w23[1], w45[0], w45[1]};
#pragma unroll
        for (int nn = 0; nn < 4; ++nn)
#pragma unroll
            for (int ff = 0; ff < 6; ++ff) acc[nn][ff] += a[nn] * w[ff];
    }
    __syncthreads();  // done reading hsT/Ws

    // write hm (relu) transposed; reload Ws = W2
#pragma unroll
    for (int nn = 0; nn < 4; ++nn)
#pragma unroll
        for (int ff = 0; ff < 6; ++ff) {
            float v = acc[nn][ff];
            hsT[6 * fg + ff][4 * ng + nn] = v > 0.f ? v : 0.f;
        }
    for (int i = tid; i < 96 * 96 / 4; i += 256)
        ((f32x4*)Ws)[i] = ((const f32x4*)W2g)[i];
    __syncthreads();

#pragma unroll
    for (int ff = 0; ff < 6; ++ff) {
        const float b = b2g[6 * fg + ff];
        acc[0][ff] = b; acc[1][ff] = b; acc[2][ff] = b; acc[3][ff] = b;
    }
    for (int k = 0; k < 96; ++k) {
        const f32x4 a = *(const f32x4*)&hsT[k][4 * ng];
        const float* wr = &Ws[k * 96 + 6 * fg];
        const f32x2 w01 = *(const f32x2*)(wr);
        const f32x2 w23 = *(const f32x2*)(wr + 2);
        const f32x2 w45 = *(const f32x2*)(wr + 4);
        const float w[6] = {w01[0], w01[1], w23[0], w23[1], w45[0], w45[1]};
#pragma unroll
        for (int nn = 0; nn < 4; ++nn)
#pragma unroll
            for (int ff = 0; ff < 6; ++ff) acc[nn][ff] += a[nn] * w[ff];
    }

    // global store o from regs (coalesced-ish: 16 fg threads cover a row)
#pragma unroll
    for (int nn = 0; nn < 4; ++nn) {
        const int n = n0 + 4 * ng + nn;
        if (n < N_NODES) {
            float* o = buf + (size_t)n * 96 + 6 * fg;
            *(f32x2*)(o)     = (f32x2){acc[nn][0], acc[nn][1]};
            *(f32x2*)(o + 2) = (f32x2){acc[nn][2], acc[nn][3]};
            *(f32x2*)(o + 4) = (f32x2){acc[nn][4], acc[nn][5]};
        }
    }

    __syncthreads();  // done reading hsT (GEMM2)
#pragma unroll
    for (int nn = 0; nn < 4; ++nn)
#pragma unroll
        for (int ff = 0; ff < 6; ++ff)
            hsT[6 * fg + ff][4 * ng + nn] = acc[nn][ff];
    __syncthreads();

    if (tid < 96) {
        int nmax = N_NODES - n0;
        if (nmax > MTILE) nmax = MTILE;
        float s = 0.f, s2 = 0.f;
        for (int n = 0; n < nmax; ++n) {
            const float v = hsT[tid][n];
            s += v; s2 += v * v;
        }
        atomicAdd(&stats[tid], s);
        atomicAdd(&stats[96 + tid], s2);
    }
}

// ---------------------------------------------------------------------------
// bn v2: finalize + affine + ReLU, float4 streaming.
// ---------------------------------------------------------------------------
__global__ __launch_bounds__(256) void bn_kernel(
    const float* __restrict__ h2, const float* __restrict__ stats,
    const float* __restrict__ gamma, const float* __restrict__ beta,
    float* __restrict__ out) {
    __shared__ float sc[96], sh[96];
    const int tid = threadIdx.x;
    if (tid < 96) {
        const float inv_n = 1.f / (float)N_NODES;
        const float mean = stats[tid] * inv_n;
        float var = stats[96 + tid] * inv_n - mean * mean;
        var = var > 0.f ? var : 0.f;
        const float s = gamma[tid] * rsqrtf(var + BN_EPS);
        sc[tid] = s;
        sh[tid] = beta[tid] - mean * s;
    }
    __syncthreads();
    const int total4 = N_NODES * 96 / 4;
    for (int i = blockIdx.x * blockDim.x + tid; i < total4;
         i += gridDim.x * blockDim.x) {
        f32x4 v = ((const f32x4*)h2)[i];
        const int jb = (i * 4) % 96;
#pragma unroll
        for (int c = 0; c < 4; ++c) {
            float u = v[c] * sc[jb + c] + sh[jb + c];
            v[c] = u > 0.f ? u : 0.f;
        }
        ((f32x4*)out)[i] = v;
    }
}

// ---------------------------------------------------------------------------
extern "C" void kernel_launch(void* const* d_in, const int* in_sizes, int n_in,
                              void* d_out, int out_size, void* d_ws,
                              size_t ws_size, hipStream_t stream) {
    const float* x     = (const float*)d_in[0];
    const int*   ei    = (const int*)d_in[1];
    const float* ea    = (const float*)d_in[2];
    const float* We    = (const float*)d_in[3];
    const float* be    = (const float*)d_in[4];
    const float* W1    = (const float*)d_in[5];
    const float* b1    = (const float*)d_in[6];
    const float* W2    = (const float*)d_in[7];
    const float* b2    = (const float*)d_in[8];
    const float* gamma = (const float*)d_in[9];
    const float* beta  = (const float*)d_in[10];
    float* out = (float*)d_out;

    float* ws    = (float*)d_ws;
    float* hbuf  = ws;              // 4.8M floats: node_aggr writes h, mlp -> o
    float* stats = ws + OFF_STATS;
    int*   flag  = (int*)(ws + OFF_FLAG);

    // edge-sort scratch lives in d_out; bn_kernel (last) overwrites it.
    int* scratch    = (int*)d_out;
    int* sorted_eid = scratch + SC_SORTED;
    int* offsets    = scratch + SC_OFFSETS;
    int* deg        = scratch + SC_DEG;
    int* cursor     = scratch + SC_CURSOR;

    hipMemsetAsync((void*)stats, 0, 256 * sizeof(float), stream);
    hipMemsetAsync((void*)deg, 0, N_NODES * sizeof(int), stream);

    detect_kernel<<<1, 1024, 0, stream>>>(ei, flag);
    hist_kernel<<<1024, 256, 0, stream>>>(ei, flag, deg);
    scan_kernel<<<1, 1024, 0, stream>>>(deg, offsets, cursor);
    scatter_kernel<<<1024, 256, 0, stream>>>(ei, flag, cursor, sorted_eid);
    node_aggr_kernel<<<1024, 256, 0, stream>>>(x, ei, ea, We, be, sorted_eid,
                                               offsets, flag, hbuf);
    mlp_kernel<<<(N_NODES + MTILE - 1) / MTILE, 256, 0, stream>>>(
        hbuf, W1, b1, W2, b2, stats);
    bn_kernel<<<1024, 256, 0, stream>>>(hbuf, stats, gamma, beta, out);
}

// Round 2
// 392.818 us; speedup vs baseline: 1.3476x; 1.3476x over previous
//
#include <hip/hip_runtime.h>

typedef unsigned short ushort_t;
typedef unsigned int uint_t;
typedef __attribute__((ext_vector_type(8))) short bf16x8;
typedef __attribute__((ext_vector_type(4))) float f32x4;
typedef __attribute__((ext_vector_type(2))) float f32x2;

#define N_NODES 50000
#define N_EDGES 800000
#define BN_EPS 1e-5f

// ws layout (floats): [0 .. 4800000) h buffer (node_aggr writes h = x + sum(msg),
//                     mlp overwrites with o rows)   [4800000..4800192) BN stats
//                     [4800192] edge_index dtype flag (1 = int64)
#define OFF_STATS 4800000
#define OFF_FLAG  4800192

// scratch carved out of d_out (ints) — consumed before bn_kernel writes out:
#define SC_PAIR    0        // int2[800000]  (eid, src) sorted by dst
#define SC_OFFSETS 1600000  // int[50001]
#define SC_DEG     1650016  // int[50000]
#define SC_RANK    1700032  // int[800000]   rank of edge within its dst bucket
#define SC_BSUM    2500032  // int[196]
#define SC_BBASE   2500288  // int[196]

#define NB_SCAN 196  // ceil(50000/256)

__device__ __forceinline__ ushort_t f2bf(float f) {
    uint_t u = __float_as_uint(f);
    uint_t r = ((u >> 16) & 1u) + 0x7fffu;  // RNE
    return (ushort_t)((u + r) >> 16);
}

// ---------------------------------------------------------------------------
// detect: int64 vs int32 edge_index. int64 data (<50000) => every odd int32
// word is 0. 4096 samples, all < 1.6M (in-bounds under either layout).
// ---------------------------------------------------------------------------
__global__ __launch_bounds__(1024) void detect_kernel(const int* __restrict__ ei,
                                                      int* __restrict__ flag) {
    __shared__ int any_nonzero;
    if (threadIdx.x == 0) any_nonzero = 0;
    __syncthreads();
    int nz = 0;
#pragma unroll
    for (int q = 0; q < 4; ++q) {
        int p = 1 + 2 * (threadIdx.x * 4 + q) * 195;  // odd, <= 1,598,051
        if (ei[p] != 0) nz = 1;
    }
    if (nz) atomicOr(&any_nonzero, 1);
    __syncthreads();
    if (threadIdx.x == 0) *flag = any_nonzero ? 0 : 1;
}

// ---------------------------------------------------------------------------
// hist: deg[dst]++ for every valid edge; the returned old value IS the
// edge's rank within its dst bucket — store it, so scatter needs no atomics.
// ---------------------------------------------------------------------------
__global__ __launch_bounds__(256) void hist_kernel(const int* __restrict__ ei,
                                                   const int* __restrict__ flag,
                                                   int* __restrict__ deg,
                                                   int* __restrict__ rank) {
    const int is64 = *flag;
    const int stride = gridDim.x * blockDim.x;
    for (int e = blockIdx.x * blockDim.x + threadIdx.x; e < N_EDGES; e += stride) {
        int s, d;
        if (is64) { s = ei[2 * e]; d = ei[2 * N_EDGES + 2 * e]; }
        else      { s = ei[e];     d = ei[N_EDGES + e]; }
        if ((uint_t)s < N_NODES && (uint_t)d < N_NODES)
            rank[e] = atomicAdd(&deg[d], 1);
    }
}

// ---------------------------------------------------------------------------
// 3-phase coalesced multi-block scan of deg[50000] -> offsets[50001].
// ---------------------------------------------------------------------------
__global__ __launch_bounds__(256) void scan1_kernel(const int* __restrict__ deg,
                                                    int* __restrict__ bsum) {
    __shared__ int sd[256];
    const int t = threadIdx.x;
    const int i = blockIdx.x * 256 + t;
    sd[t] = (i < N_NODES) ? deg[i] : 0;
    __syncthreads();
    for (int s = 128; s > 0; s >>= 1) {
        if (t < s) sd[t] += sd[t + s];
        __syncthreads();
    }
    if (t == 0) bsum[blockIdx.x] = sd[0];
}

__global__ __launch_bounds__(256) void scan2_kernel(const int* __restrict__ bsum,
                                                    int* __restrict__ bbase) {
    __shared__ int sd[256];
    const int t = threadIdx.x;
    int v = (t < NB_SCAN) ? bsum[t] : 0;
    sd[t] = v;
    __syncthreads();
    for (int off = 1; off < 256; off <<= 1) {
        int u = (t >= off) ? sd[t - off] : 0;
        __syncthreads();
        sd[t] += u;
        __syncthreads();
    }
    if (t < NB_SCAN) bbase[t] = sd[t] - v;  // exclusive
}

__global__ __launch_bounds__(256) void scan3_kernel(const int* __restrict__ deg,
                                                    const int* __restrict__ bbase,
                                                    int* __restrict__ offsets) {
    __shared__ int sd[256];
    const int t = threadIdx.x;
    const int i = blockIdx.x * 256 + t;
    const int v = (i < N_NODES) ? deg[i] : 0;
    sd[t] = v;
    __syncthreads();
    for (int off = 1; off < 256; off <<= 1) {
        int u = (t >= off) ? sd[t - off] : 0;
        __syncthreads();
        sd[t] += u;
        __syncthreads();
    }
    const int excl = bbase[blockIdx.x] + sd[t] - v;
    if (i < N_NODES) offsets[i] = excl;
    if (i == N_NODES - 1) offsets[N_NODES] = excl + v;
}

// ---------------------------------------------------------------------------
// scatter (atomic-free): pos = offsets[dst] + rank[e]; pair = (eid, src).
// node_aggr then never touches edge_index.
// ---------------------------------------------------------------------------
__global__ __launch_bounds__(256) void scatter_kernel(const int* __restrict__ ei,
                                                      const int* __restrict__ flag,
                                                      const int* __restrict__ offsets,
                                                      const int* __restrict__ rank,
                                                      int2* __restrict__ pair) {
    const int is64 = *flag;
    const int stride = gridDim.x * blockDim.x;
    for (int e = blockIdx.x * blockDim.x + threadIdx.x; e < N_EDGES; e += stride) {
        int s, d;
        if (is64) { s = ei[2 * e]; d = ei[2 * N_EDGES + 2 * e]; }
        else      { s = ei[e];     d = ei[N_EDGES + e]; }
        if ((uint_t)s < N_NODES && (uint_t)d < N_NODES) {
            const int pos = offsets[d] + rank[e];
            pair[pos] = make_int2(e, s);
        }
    }
}

// ---------------------------------------------------------------------------
// node_aggr: one wave per node (grid-stride). For each 16-edge chunk of the
// node's sorted edge list:
//   proj[16e x 96f] = ea[eids] @ We  via 6x mfma 16x16x32 bf16
//   (A[m=t][k=q*8+j], C row m=q*4+r col t  [m89 layout])
//   part[f] += relu(proj + be + x[src])  summed over this quad's 4 rows.
// Butterfly across quads, add x[n], ONE plain store per element.
// ---------------------------------------------------------------------------
__global__ __launch_bounds__(256) void node_aggr_kernel(
    const float* __restrict__ x, const float* __restrict__ ea,
    const float* __restrict__ We, const float* __restrict__ be,
    const int2* __restrict__ pair, const int* __restrict__ offsets,
    float* __restrict__ hbuf) {
    const int lane = threadIdx.x & 63;
    const int q = lane >> 4;   // quad 0..3
    const int t = lane & 15;   // 0..15
    const int wav = blockIdx.x * (blockDim.x >> 6) + (threadIdx.x >> 6);
    const int nwav = gridDim.x * (blockDim.x >> 6);

    bf16x8 Bf[6];
    float ben[6];
#pragma unroll
    for (int f = 0; f < 6; ++f) {
        const int n = t + 16 * f;
#pragma unroll
        for (int j = 0; j < 8; ++j) {
            const int k = q * 8 + j;
            Bf[f][j] = (short)f2bf(We[k * 96 + n]);
        }
        ben[f] = be[n];
    }

    for (int n = wav; n < N_NODES; n += nwav) {
        const int off = offsets[n];
        const int deg = offsets[n + 1] - off;

        float part[6];
#pragma unroll
        for (int f = 0; f < 6; ++f) part[f] = 0.f;

        for (int c0 = 0; c0 < deg; c0 += 16) {
            const int rem = deg - c0;  // >= 1; valid slots = min(rem,16)
            int eid_t = -1, src_t = -1;
            if (t < rem) {
                const int2 p = pair[off + c0 + t];
                eid_t = p.x;
                src_t = p.y;
            }
            bf16x8 A = {0, 0, 0, 0, 0, 0, 0, 0};
            if (eid_t >= 0) {
                const float* row = ea + (size_t)eid_t * 32 + q * 8;
                f32x4 a0 = *(const f32x4*)(row);
                f32x4 a1 = *(const f32x4*)(row + 4);
#pragma unroll
                for (int j = 0; j < 4; ++j) {
                    A[j] = (short)f2bf(a0[j]);
                    A[4 + j] = (short)f2bf(a1[j]);
                }
            }

            f32x4 acc[6];
#pragma unroll
            for (int f = 0; f < 6; ++f) {
                f32x4 z = {0.f, 0.f, 0.f, 0.f};
                acc[f] = __builtin_amdgcn_mfma_f32_16x16x32_bf16(A, Bf[f], z, 0, 0, 0);
            }

            // srcs of this quad's 4 rows (slot m held by lane m, m<16).
            int s_r[4];
#pragma unroll
            for (int r = 0; r < 4; ++r) s_r[r] = __shfl(src_t, q * 4 + r);

#pragma unroll
            for (int r = 0; r < 4; ++r) {
                const int m = q * 4 + r;
                if (m < rem) {
                    const float* xrow = x + (size_t)s_r[r] * 96;
#pragma unroll
                    for (int f = 0; f < 6; ++f) {
                        float v = acc[f][r] + ben[f] + xrow[t + 16 * f];
                        part[f] += v > 0.f ? v : 0.f;
                    }
                }
            }
        }

        // reduce across the 4 quads
#pragma unroll
        for (int f = 0; f < 6; ++f) {
            part[f] += __shfl_xor(part[f], 16);
            part[f] += __shfl_xor(part[f], 32);
        }

        if (q == 0) {
            const float* xn = x + (size_t)n * 96;
            float* hn = hbuf + (size_t)n * 96;
#pragma unroll
            for (int f = 0; f < 6; ++f) {
                const int col = t + 16 * f;
                hn[col] = part[f] + xn[col];
            }
        }
    }
}

// ---------------------------------------------------------------------------
// mlp v2 (fp32, register-tiled): 64-node tile, 256 threads.
// thread (fg=tid&15, ng=tid>>4): 4 nodes x 6 features, 24 accumulators.
// hsT[k][n] (pad 68: bank = (4k+n)%32, conflict-free reads), Ws[96*96].
// ---------------------------------------------------------------------------
#define MTILE 64
__global__ __launch_bounds__(256) void mlp_kernel(
    float* buf, const float* __restrict__ W1g, const float* __restrict__ b1g,
    const float* __restrict__ W2g, const float* __restrict__ b2g,
    float* __restrict__ stats) {
    __shared__ float Ws[96 * 96];
    __shared__ float hsT[96][68];

    const int tid = threadIdx.x;
    const int fg = tid & 15;
    const int ng = tid >> 4;
    const int n0 = blockIdx.x * MTILE;

    for (int i = tid; i < 96 * 96 / 4; i += 256)
        ((f32x4*)Ws)[i] = ((const f32x4*)W1g)[i];
    for (int i = tid; i < MTILE * 96 / 4; i += 256) {
        const int base = i * 4;
        const int nn = base / 96, k = base - nn * 96;
        f32x4 v = {0.f, 0.f, 0.f, 0.f};
        if (n0 + nn < N_NODES)
            v = *(const f32x4*)(buf + (size_t)(n0 + nn) * 96 + k);
        hsT[k][nn] = v[0]; hsT[k + 1][nn] = v[1];
        hsT[k + 2][nn] = v[2]; hsT[k + 3][nn] = v[3];
    }
    __syncthreads();

    float acc[4][6];
#pragma unroll
    for (int ff = 0; ff < 6; ++ff) {
        const float b = b1g[6 * fg + ff];
        acc[0][ff] = b; acc[1][ff] = b; acc[2][ff] = b; acc[3][ff] = b;
    }
    for (int k = 0; k < 96; ++k) {
        const f32x4 a = *(const f32x4*)&hsT[k][4 * ng];
        const float* wr = &Ws[k * 96 + 6 * fg];
        const f32x2 w01 = *(const f32x2*)(wr);
        const f32x2 w23 = *(const f32x2*)(wr + 2);
        const f32x2 w45 = *(const f32x2*)(wr + 4);
        const float w[6] = {w01[0], w01[1], w23[0], w23[1], w45[0], w45[1]};
#pragma unroll
        for (int nn = 0; nn < 4; ++nn)
#pragma unroll
            for (int ff = 0; ff < 6; ++ff) acc[nn][ff] += a[nn] * w[ff];
    }
    __syncthreads();  // done reading hsT/Ws

    // write hm (relu) transposed; reload Ws = W2
#pragma unroll
    for (int nn = 0; nn < 4; ++nn)
#pragma unroll
        for (int ff = 0; ff < 6; ++ff) {
            float v = acc[nn][ff];
            hsT[6 * fg + ff][4 * ng + nn] = v > 0.f ? v : 0.f;
        }
    for (int i = tid; i < 96 * 96 / 4; i += 256)
        ((f32x4*)Ws)[i] = ((const f32x4*)W2g)[i];
    __syncthreads();

#pragma unroll
    for (int ff = 0; ff < 6; ++ff) {
        const float b = b2g[6 * fg + ff];
        acc[0][ff] = b; acc[1][ff] = b; acc[2][ff] = b; acc[3][ff] = b;
    }
    for (int k = 0; k < 96; ++k) {
        const f32x4 a = *(const f32x4*)&hsT[k][4 * ng];
        const float* wr = &Ws[k * 96 + 6 * fg];
        const f32x2 w01 = *(const f32x2*)(wr);
        const f32x2 w23 = *(const f32x2*)(wr + 2);
        const f32x2 w45 = *(const f32x2*)(wr + 4);
        const float w[6] = {w01[0], w01[1], w23[0], w23[1], w45[0], w45[1]};
#pragma unroll
        for (int nn = 0; nn < 4; ++nn)
#pragma unroll
            for (int ff = 0; ff < 6; ++ff) acc[nn][ff] += a[nn] * w[ff];
    }

    // global store o from regs (coalesced-ish: 16 fg threads cover a row)
#pragma unroll
    for (int nn = 0; nn < 4; ++nn) {
        const int n = n0 + 4 * ng + nn;
        if (n < N_NODES) {
            float* o = buf + (size_t)n * 96 + 6 * fg;
            *(f32x2*)(o)     = (f32x2){acc[nn][0], acc[nn][1]};
            *(f32x2*)(o + 2) = (f32x2){acc[nn][2], acc[nn][3]};
            *(f32x2*)(o + 4) = (f32x2){acc[nn][4], acc[nn][5]};
        }
    }

    __syncthreads();  // done reading hsT (GEMM2)
#pragma unroll
    for (int nn = 0; nn < 4; ++nn)
#pragma unroll
        for (int ff = 0; ff < 6; ++ff)
            hsT[6 * fg + ff][4 * ng + nn] = acc[nn][ff];
    __syncthreads();

    if (tid < 96) {
        int nmax = N_NODES - n0;
        if (nmax > MTILE) nmax = MTILE;
        float s = 0.f, s2 = 0.f;
        for (int n = 0; n < nmax; ++n) {
            const float v = hsT[tid][n];
            s += v; s2 += v * v;
        }
        atomicAdd(&stats[tid], s);
        atomicAdd(&stats[96 + tid], s2);
    }
}

// ---------------------------------------------------------------------------
// bn v2: finalize + affine + ReLU, float4 streaming.
// ---------------------------------------------------------------------------
__global__ __launch_bounds__(256) void bn_kernel(
    const float* __restrict__ h2, const float* __restrict__ stats,
    const float* __restrict__ gamma, const float* __restrict__ beta,
    float* __restrict__ out) {
    __shared__ float sc[96], sh[96];
    const int tid = threadIdx.x;
    if (tid < 96) {
        const float inv_n = 1.f / (float)N_NODES;
        const float mean = stats[tid] * inv_n;
        float var = stats[96 + tid] * inv_n - mean * mean;
        var = var > 0.f ? var : 0.f;
        const float s = gamma[tid] * rsqrtf(var + BN_EPS);
        sc[tid] = s;
        sh[tid] = beta[tid] - mean * s;
    }
    __syncthreads();
    const int total4 = N_NODES * 96 / 4;
    for (int i = blockIdx.x * blockDim.x + tid; i < total4;
         i += gridDim.x * blockDim.x) {
        f32x4 v = ((const f32x4*)h2)[i];
        const int jb = (i * 4) % 96;
#pragma unroll
        for (int c = 0; c < 4; ++c) {
            float u = v[c] * sc[jb + c] + sh[jb + c];
            v[c] = u > 0.f ? u : 0.f;
        }
        ((f32x4*)out)[i] = v;
    }
}

// ---------------------------------------------------------------------------
extern "C" void kernel_launch(void* const* d_in, const int* in_sizes, int n_in,
                              void* d_out, int out_size, void* d_ws,
                              size_t ws_size, hipStream_t stream) {
    const float* x     = (const float*)d_in[0];
    const int*   ei    = (const int*)d_in[1];
    const float* ea    = (const float*)d_in[2];
    const float* We    = (const float*)d_in[3];
    const float* be    = (const float*)d_in[4];
    const float* W1    = (const float*)d_in[5];
    const float* b1    = (const float*)d_in[6];
    const float* W2    = (const float*)d_in[7];
    const float* b2    = (const float*)d_in[8];
    const float* gamma = (const float*)d_in[9];
    const float* beta  = (const float*)d_in[10];
    float* out = (float*)d_out;

    float* ws    = (float*)d_ws;
    float* hbuf  = ws;              // 4.8M floats: node_aggr writes h, mlp -> o
    float* stats = ws + OFF_STATS;
    int*   flag  = (int*)(ws + OFF_FLAG);

    // edge-sort scratch lives in d_out; bn_kernel (last) overwrites it.
    int*  scratch = (int*)d_out;
    int2* pair    = (int2*)(scratch + SC_PAIR);
    int*  offsets = scratch + SC_OFFSETS;
    int*  deg     = scratch + SC_DEG;
    int*  rank    = scratch + SC_RANK;
    int*  bsum    = scratch + SC_BSUM;
    int*  bbase   = scratch + SC_BBASE;

    hipMemsetAsync((void*)stats, 0, 256 * sizeof(float), stream);
    hipMemsetAsync((void*)deg, 0, N_NODES * sizeof(int), stream);

    detect_kernel<<<1, 1024, 0, stream>>>(ei, flag);
    hist_kernel<<<1024, 256, 0, stream>>>(ei, flag, deg, rank);
    scan1_kernel<<<NB_SCAN, 256, 0, stream>>>(deg, bsum);
    scan2_kernel<<<1, 256, 0, stream>>>(bsum, bbase);
    scan3_kernel<<<NB_SCAN, 256, 0, stream>>>(deg, bbase, offsets);
    scatter_kernel<<<1024, 256, 0, stream>>>(ei, flag, offsets, rank, pair);
    node_aggr_kernel<<<2048, 256, 0, stream>>>(x, ea, We, be, pair, offsets,
                                               hbuf);
    mlp_kernel<<<(N_NODES + MTILE - 1) / MTILE, 256, 0, stream>>>(
        hbuf, W1, b1, W2, b2, stats);
    bn_kernel<<<1024, 256, 0, stream>>>(hbuf, stats, gamma, beta, out);
}